// Round 1
// baseline (95.430 us; speedup 1.0000x reference)
//
#include <hip/hip_runtime.h>

typedef unsigned short u16;
typedef unsigned int   u32;
typedef u16   u16x4 __attribute__((ext_vector_type(4)));
typedef u16   u16x8 __attribute__((ext_vector_type(8)));
typedef short s16x8 __attribute__((ext_vector_type(8)));
typedef float f32x4 __attribute__((ext_vector_type(4)));

#define S_TOK 4096
#define MDIM  2048
#define NDIM  2048
#define HDIM  1024
#define TDIM  512

__device__ __forceinline__ u16 f2bf(float f) {
  u32 u = __float_as_uint(f);
  u = u + 0x7fffu + ((u >> 16) & 1u);   // round-to-nearest-even
  return (u16)(u >> 16);
}

// ---- w1 [E][M][H] fp32  ->  w1t [E*H][M] bf16 (transposed, K-contiguous) ----
__global__ __launch_bounds__(256) void prep_w1t(const float* __restrict__ w1,
                                                u16* __restrict__ w1t) {
  __shared__ float tile[32][33];
  int bid = blockIdx.x;
  int e   = bid >> 11;           // 2048 tiles per expert
  int idx = bid & 2047;
  int m0  = (idx >> 5) << 5;     // 64 m-tiles
  int h0  = (idx & 31) << 5;     // 32 h-tiles
  int t = threadIdx.x;
  int r = t >> 3, q = t & 7;
  const float* src = w1 + ((size_t)e * MDIM + (m0 + r)) * HDIM + h0 + q * 4;
  f32x4 v = *(const f32x4*)src;
  tile[r][q*4+0] = v[0]; tile[r][q*4+1] = v[1];
  tile[r][q*4+2] = v[2]; tile[r][q*4+3] = v[3];
  __syncthreads();
  u16x4 o;
  o[0] = f2bf(tile[q*4+0][r]);
  o[1] = f2bf(tile[q*4+1][r]);
  o[2] = f2bf(tile[q*4+2][r]);
  o[3] = f2bf(tile[q*4+3][r]);
  u16* dst = w1t + ((size_t)e * HDIM + (h0 + r)) * MDIM + m0 + q * 4;
  *(u16x4*)dst = o;
}

// ---- w2sum[n] = sum_m w2[e,h,m]  (n = e*H + h);  b2sum[e] = sum_m b2[e,m] ----
__global__ __launch_bounds__(256) void prep_sums(const float* __restrict__ w2,
                                                 const float* __restrict__ b2,
                                                 float* __restrict__ w2sum,
                                                 float* __restrict__ b2sum) {
  int row  = blockIdx.x * 4 + (threadIdx.x >> 6);
  int lane = threadIdx.x & 63;
  const float* src;
  if (row < NDIM)          src = w2 + (size_t)row * MDIM;
  else if (row < NDIM + 2) src = b2 + (size_t)(row - NDIM) * MDIM;
  else return;
  float acc = 0.f;
  for (int m = lane * 4; m < MDIM; m += 256) {
    f32x4 v = *(const f32x4*)(src + m);
    acc += v[0] + v[1] + v[2] + v[3];
  }
  #pragma unroll
  for (int off = 32; off; off >>= 1) acc += __shfl_xor(acc, off);
  if (lane == 0) {
    if (row < NDIM) w2sum[row] = acc;
    else            b2sum[row - NDIM] = acc;
  }
}

// ---- fp32 gate: logits = x @ wg, softmax over E=2 ----
__global__ __launch_bounds__(256) void gate_kernel(const float* __restrict__ x,
                                                   const float* __restrict__ wg,
                                                   float* __restrict__ g) {
  int s    = blockIdx.x * 4 + (threadIdx.x >> 6);
  int lane = threadIdx.x & 63;
  const float* xr = x + (size_t)s * MDIM;
  float l0 = 0.f, l1 = 0.f;
  for (int m = lane * 4; m < MDIM; m += 256) {
    f32x4 xv = *(const f32x4*)(xr + m);
    f32x4 wa = *(const f32x4*)(wg + 2 * m);      // (m,0) (m,1) (m+1,0) (m+1,1)
    f32x4 wb = *(const f32x4*)(wg + 2 * m + 4);  // (m+2,0) ...
    l0 += xv[0]*wa[0] + xv[1]*wa[2] + xv[2]*wb[0] + xv[3]*wb[2];
    l1 += xv[0]*wa[1] + xv[1]*wa[3] + xv[2]*wb[1] + xv[3]*wb[3];
  }
  #pragma unroll
  for (int off = 32; off; off >>= 1) {
    l0 += __shfl_xor(l0, off);
    l1 += __shfl_xor(l1, off);
  }
  if (lane == 0) {
    float mx = fmaxf(l0, l1);
    float e0 = expf(l0 - mx), e1 = expf(l1 - mx);
    float inv = 1.f / (e0 + e1);
    g[2*s]   = e0 * inv;
    g[2*s+1] = e1 * inv;
  }
}

// ---- main GEMM [S,M]x[M,N=E*H] bf16 MFMA, fused relu*w2sum row-reduce ----
#define BM 128
#define BN 128
#define BK 32
#define LDST 48   // padded LDS row stride (bf16 elems); bank-uniform, 16B-aligned rows

__global__ __launch_bounds__(256) void gemm_fused(const float* __restrict__ x,
                                                  const u16*  __restrict__ w1t,
                                                  const float* __restrict__ b1,
                                                  const float* __restrict__ w2sum,
                                                  float* __restrict__ ssum) {
  __shared__ u16 As[BM * LDST];
  __shared__ u16 Bs[BN * LDST];

  int bid  = blockIdx.x;
  int tile = (bid & 7) * 64 + (bid >> 3);   // XCD-aware swizzle (512 % 8 == 0)
  int bn = tile & 15;
  int bm = tile >> 4;
  int gs0 = bm * BM;
  int gn0 = bn * BN;

  int tid  = threadIdx.x;
  int lane = tid & 63;
  int wid  = tid >> 6;
  int wr = wid >> 1, wc = wid & 1;          // 2x2 waves, 64x64 each
  int fr = lane & 15, fg = lane >> 4;

  f32x4 acc[4][4] = {};

  for (int kt = 0; kt < MDIM / BK; ++kt) {
    int k0 = kt * BK;
    // stage A: x fp32 -> bf16 LDS [row][k]
    #pragma unroll
    for (int i = 0; i < 4; ++i) {
      int slot = tid + i * 256;
      int r = slot >> 3, cq = slot & 7;
      f32x4 v = *(const f32x4*)(x + (size_t)(gs0 + r) * MDIM + k0 + cq * 4);
      u16x4 o; o[0]=f2bf(v[0]); o[1]=f2bf(v[1]); o[2]=f2bf(v[2]); o[3]=f2bf(v[3]);
      *(u16x4*)(&As[r * LDST + cq * 4]) = o;
    }
    // stage B: w1t bf16 [n][k] -> LDS [n][k]
    #pragma unroll
    for (int i = 0; i < 2; ++i) {
      int slot = tid + i * 256;
      int n = slot >> 2, q = slot & 3;
      u16x8 v = *(const u16x8*)(w1t + (size_t)(gn0 + n) * MDIM + k0 + q * 8);
      *(u16x8*)(&Bs[n * LDST + q * 8]) = v;
    }
    __syncthreads();
    s16x8 af[4], bfr[4];
    #pragma unroll
    for (int i = 0; i < 4; ++i) {
      af[i]  = *(const s16x8*)(&As[(wr * 64 + i * 16 + fr) * LDST + fg * 8]);
      bfr[i] = *(const s16x8*)(&Bs[(wc * 64 + i * 16 + fr) * LDST + fg * 8]);
    }
    #pragma unroll
    for (int i = 0; i < 4; ++i)
      #pragma unroll
      for (int j = 0; j < 4; ++j)
        acc[i][j] = __builtin_amdgcn_mfma_f32_16x16x32_bf16(af[i], bfr[j], acc[i][j], 0, 0, 0);
    __syncthreads();
  }

  // epilogue: relu(acc + b1) * w2sum, reduce across 64 cols -> ssum[e][s]
  int e = gn0 >> 10;  // whole block within one expert (1024 % BN == 0)
  float b1v[4], w2v[4];
  #pragma unroll
  for (int j = 0; j < 4; ++j) {
    int n = gn0 + wc * 64 + j * 16 + fr;
    b1v[j] = b1[n];
    w2v[j] = w2sum[n];
  }
  #pragma unroll
  for (int i = 0; i < 4; ++i) {
    #pragma unroll
    for (int r = 0; r < 4; ++r) {
      float sv = 0.f;
      #pragma unroll
      for (int j = 0; j < 4; ++j)
        sv += fmaxf(acc[i][j][r] + b1v[j], 0.f) * w2v[j];
      sv += __shfl_xor(sv, 1);
      sv += __shfl_xor(sv, 2);
      sv += __shfl_xor(sv, 4);
      sv += __shfl_xor(sv, 8);
      if (fr == 0) {
        int s = gs0 + wr * 64 + i * 16 + fg * 4 + r;
        atomicAdd(&ssum[(size_t)e * S_TOK + s], sv);
      }
    }
  }
}

// ---- summed = g0*(ssum0+b2sum0)+g1*(ssum1+b2sum1); log_softmax over T ----
__global__ __launch_bounds__(512) void finalize(const float* __restrict__ g,
                                                const float* __restrict__ ssum,
                                                const float* __restrict__ b2sum,
                                                float* __restrict__ out) {
  __shared__ float sA[8];
  __shared__ float sB[2];
  int b = blockIdx.x;
  int t = threadIdx.x;
  int s = b * TDIM + t;
  int lane = t & 63, wid = t >> 6;
  float g0 = g[2*s], g1 = g[2*s+1];
  float v = g0 * (ssum[s] + b2sum[0]) + g1 * (ssum[S_TOK + s] + b2sum[1]);
  float m = v;
  #pragma unroll
  for (int off = 32; off; off >>= 1) m = fmaxf(m, __shfl_xor(m, off));
  if (lane == 0) sA[wid] = m;
  __syncthreads();
  if (t == 0) {
    float mm = sA[0];
    #pragma unroll
    for (int i = 1; i < 8; ++i) mm = fmaxf(mm, sA[i]);
    sB[0] = mm;
  }
  __syncthreads();
  float gm = sB[0];
  float ex = expf(v - gm);
  float sum = ex;
  #pragma unroll
  for (int off = 32; off; off >>= 1) sum += __shfl_xor(sum, off);
  if (lane == 0) sA[wid] = sum;
  __syncthreads();
  if (t == 0) {
    float ss = 0.f;
    #pragma unroll
    for (int i = 0; i < 8; ++i) ss += sA[i];
    sB[1] = logf(ss);
  }
  __syncthreads();
  out[s] = v - gm - sB[1];
}

extern "C" void kernel_launch(void* const* d_in, const int* in_sizes, int n_in,
                              void* d_out, int out_size, void* d_ws, size_t ws_size,
                              hipStream_t stream) {
  const float* x  = (const float*)d_in[0];
  const float* wg = (const float*)d_in[1];
  const float* w1 = (const float*)d_in[2];
  const float* b1 = (const float*)d_in[3];
  const float* w2 = (const float*)d_in[4];
  const float* b2 = (const float*)d_in[5];
  float* out = (float*)d_out;

  char* ws = (char*)d_ws;
  u16*   w1t   = (u16*)ws;                    // 2048*2048*2 = 8,388,608 B
  float* ssum  = (float*)(ws + 8388608);      // 2*4096*4   = 32,768 B
  float* gbuf  = (float*)(ws + 8421376);      // 4096*2*4   = 32,768 B
  float* w2sum = (float*)(ws + 8454144);      // 2048*4     = 8,192 B
  float* b2sum = (float*)(ws + 8462336);      // 2*4        = 8 B

  hipMemsetAsync(ssum, 0, S_TOK * 2 * sizeof(float), stream);
  hipLaunchKernelGGL(prep_w1t,   dim3(4096), dim3(256), 0, stream, w1, w1t);
  hipLaunchKernelGGL(prep_sums,  dim3(513),  dim3(256), 0, stream, w2, b2, w2sum, b2sum);
  hipLaunchKernelGGL(gate_kernel,dim3(1024), dim3(256), 0, stream, x, wg, gbuf);
  hipLaunchKernelGGL(gemm_fused, dim3(512),  dim3(256), 0, stream, x, w1t, b1, w2sum, ssum);
  hipLaunchKernelGGL(finalize,   dim3(8),    dim3(512), 0, stream, gbuf, ssum, b2sum, out);
}

// Round 2
// 69.530 us; speedup vs baseline: 1.3725x; 1.3725x over previous
//
#include <hip/hip_runtime.h>

typedef unsigned short u16;
typedef unsigned int   u32;
typedef u16   u16x4 __attribute__((ext_vector_type(4)));
typedef u16   u16x8 __attribute__((ext_vector_type(8)));
typedef short s16x8 __attribute__((ext_vector_type(8)));
typedef float f32x4 __attribute__((ext_vector_type(4)));

#define S_TOK 4096
#define MDIM  2048
#define NDIM  2048
#define HDIM  1024
#define TDIM  512

__device__ __forceinline__ u16 f2bf(float f) {
  u32 u = __float_as_uint(f);
  u = u + 0x7fffu + ((u >> 16) & 1u);   // round-to-nearest-even
  return (u16)(u >> 16);
}

__device__ __forceinline__ void gl2lds16(const void* g, void* l) {
  __builtin_amdgcn_global_load_lds(
      (const __attribute__((address_space(1))) void*)g,
      (__attribute__((address_space(3))) void*)l, 16, 0, 0);
}

// ---- w1 [E][M][H] fp32  ->  w1t [E*H][M] bf16 (transposed, K-contiguous) ----
__global__ __launch_bounds__(256) void prep_w1t(const float* __restrict__ w1,
                                                u16* __restrict__ w1t) {
  __shared__ float tile[32][33];
  int bid = blockIdx.x;
  int e   = bid >> 11;           // 2048 tiles per expert
  int idx = bid & 2047;
  int m0  = (idx >> 5) << 5;     // 64 m-tiles
  int h0  = (idx & 31) << 5;     // 32 h-tiles
  int t = threadIdx.x;
  int r = t >> 3, q = t & 7;
  const float* src = w1 + ((size_t)e * MDIM + (m0 + r)) * HDIM + h0 + q * 4;
  f32x4 v = *(const f32x4*)src;
  tile[r][q*4+0] = v[0]; tile[r][q*4+1] = v[1];
  tile[r][q*4+2] = v[2]; tile[r][q*4+3] = v[3];
  __syncthreads();
  u16x4 o;
  o[0] = f2bf(tile[q*4+0][r]);
  o[1] = f2bf(tile[q*4+1][r]);
  o[2] = f2bf(tile[q*4+2][r]);
  o[3] = f2bf(tile[q*4+3][r]);
  u16* dst = w1t + ((size_t)e * HDIM + (h0 + r)) * MDIM + m0 + q * 4;
  *(u16x4*)dst = o;
}

// ---- w2sum[n] = sum_m w2[e,h,m];  b2sum[e] = sum_m b2[e,m] ----
__global__ __launch_bounds__(256) void prep_sums(const float* __restrict__ w2,
                                                 const float* __restrict__ b2,
                                                 float* __restrict__ w2sum,
                                                 float* __restrict__ b2sum) {
  int row  = blockIdx.x * 4 + (threadIdx.x >> 6);
  int lane = threadIdx.x & 63;
  const float* src;
  if (row < NDIM)          src = w2 + (size_t)row * MDIM;
  else if (row < NDIM + 2) src = b2 + (size_t)(row - NDIM) * MDIM;
  else return;
  float acc = 0.f;
  for (int m = lane * 4; m < MDIM; m += 256) {
    f32x4 v = *(const f32x4*)(src + m);
    acc += v[0] + v[1] + v[2] + v[3];
  }
  #pragma unroll
  for (int off = 32; off; off >>= 1) acc += __shfl_xor(acc, off);
  if (lane == 0) {
    if (row < NDIM) w2sum[row] = acc;
    else            b2sum[row - NDIM] = acc;
  }
}

// ---- fp32 gate + fused x->bf16 conversion ----
__global__ __launch_bounds__(256) void gate_xbf(const float* __restrict__ x,
                                                const float* __restrict__ wg,
                                                float* __restrict__ g,
                                                u16* __restrict__ xbf) {
  int s    = blockIdx.x * 4 + (threadIdx.x >> 6);
  int lane = threadIdx.x & 63;
  const float* xr = x + (size_t)s * MDIM;
  u16* xbr = xbf + (size_t)s * MDIM;
  float l0 = 0.f, l1 = 0.f;
  for (int m = lane * 4; m < MDIM; m += 256) {
    f32x4 xv = *(const f32x4*)(xr + m);
    f32x4 wa = *(const f32x4*)(wg + 2 * m);
    f32x4 wb = *(const f32x4*)(wg + 2 * m + 4);
    l0 += xv[0]*wa[0] + xv[1]*wa[2] + xv[2]*wb[0] + xv[3]*wb[2];
    l1 += xv[0]*wa[1] + xv[1]*wa[3] + xv[2]*wb[1] + xv[3]*wb[3];
    u16x4 o; o[0]=f2bf(xv[0]); o[1]=f2bf(xv[1]); o[2]=f2bf(xv[2]); o[3]=f2bf(xv[3]);
    *(u16x4*)(xbr + m) = o;
  }
  #pragma unroll
  for (int off = 32; off; off >>= 1) {
    l0 += __shfl_xor(l0, off);
    l1 += __shfl_xor(l1, off);
  }
  if (lane == 0) {
    float mx = fmaxf(l0, l1);
    float e0 = expf(l0 - mx), e1 = expf(l1 - mx);
    float inv = 1.f / (e0 + e1);
    g[2*s]   = e0 * inv;
    g[2*s+1] = e1 * inv;
  }
}

// ---- main GEMM [S,M]x[M,N] bf16 MFMA via global_load_lds + swizzle ----
#define BM 128
#define BN 128
#define BK 64
#define KT (MDIM / BK)

__global__ __launch_bounds__(512, 4) void gemm_fused(const u16* __restrict__ xbf,
                                                     const u16* __restrict__ w1t,
                                                     const float* __restrict__ b1,
                                                     const float* __restrict__ w2sum,
                                                     float* __restrict__ ssum) {
  __shared__ u16 As[2][BM * BK];
  __shared__ u16 Bs[2][BN * BK];

  int bid  = blockIdx.x;
  int tile = (bid & 7) * 64 + (bid >> 3);   // XCD swizzle (512 % 8 == 0, bijective)
  int bn = tile & 15;
  int bm = tile >> 4;
  int gs0 = bm * BM;
  int gn0 = bn * BN;

  int tid  = threadIdx.x;
  int lane = tid & 63;
  int wid  = tid >> 6;               // 0..7
  int wr = wid >> 2, wc = wid & 3;   // 2x4 wave grid; wave tile 64x32
  int fr = lane & 15, fg = lane >> 4;

  // staging constants: wave stages 16 rows of A and 16 rows of B (2 issues of 8 rows)
  int lr = lane >> 3;                // row within 8-row issue
  int lc = (lane & 7) ^ lr;          // inverse-swizzled source chunk (rule #21)
  int row0 = wid * 16;
  const u16* asrc = xbf + (size_t)(gs0 + row0 + lr) * MDIM + lc * 8;
  const u16* bsrc = w1t + (size_t)(gn0 + row0 + lr) * MDIM + lc * 8;

  f32x4 acc[4][2] = {};

  // prologue: stage tile 0 into buffer 0
  {
    gl2lds16(asrc,            &As[0][ row0      * BK]);
    gl2lds16(asrc + 8 * MDIM, &As[0][(row0 + 8) * BK]);
    gl2lds16(bsrc,            &Bs[0][ row0      * BK]);
    gl2lds16(bsrc + 8 * MDIM, &Bs[0][(row0 + 8) * BK]);
  }

  for (int kt = 0; kt < KT; ++kt) {
    int cur = kt & 1;
    __syncthreads();   // drains vmcnt(0): tile kt is resident; prev reads done
    if (kt + 1 < KT) {
      int k0 = (kt + 1) * BK;
      gl2lds16(asrc + k0,            &As[cur ^ 1][ row0      * BK]);
      gl2lds16(asrc + k0 + 8 * MDIM, &As[cur ^ 1][(row0 + 8) * BK]);
      gl2lds16(bsrc + k0,            &Bs[cur ^ 1][ row0      * BK]);
      gl2lds16(bsrc + k0 + 8 * MDIM, &Bs[cur ^ 1][(row0 + 8) * BK]);
    }
    #pragma unroll
    for (int kk = 0; kk < 2; ++kk) {
      s16x8 af[4], bfr[2];
      #pragma unroll
      for (int i = 0; i < 4; ++i) {
        int row = wr * 64 + i * 16 + fr;
        int ch  = (fg + 4 * kk) ^ (fr & 7);   // swizzled read (matches source perm)
        af[i] = *(const s16x8*)(&As[cur][row * BK + ch * 8]);
      }
      #pragma unroll
      for (int j = 0; j < 2; ++j) {
        int row = wc * 32 + j * 16 + fr;
        int ch  = (fg + 4 * kk) ^ (fr & 7);
        bfr[j] = *(const s16x8*)(&Bs[cur][row * BK + ch * 8]);
      }
      #pragma unroll
      for (int i = 0; i < 4; ++i)
        #pragma unroll
        for (int j = 0; j < 2; ++j)
          acc[i][j] = __builtin_amdgcn_mfma_f32_16x16x32_bf16(af[i], bfr[j], acc[i][j], 0, 0, 0);
    }
  }

  // epilogue: relu(acc + b1) * w2sum, reduce across 32 cols -> ssum[e][s]
  int e = gn0 >> 10;   // whole block within one expert (1024 % BN == 0)
  float b1v[2], w2v[2];
  #pragma unroll
  for (int j = 0; j < 2; ++j) {
    int n = gn0 + wc * 32 + j * 16 + fr;
    b1v[j] = b1[n];
    w2v[j] = w2sum[n];
  }
  #pragma unroll
  for (int i = 0; i < 4; ++i) {
    #pragma unroll
    for (int r = 0; r < 4; ++r) {
      float sv = 0.f;
      #pragma unroll
      for (int j = 0; j < 2; ++j)
        sv += fmaxf(acc[i][j][r] + b1v[j], 0.f) * w2v[j];
      sv += __shfl_xor(sv, 1);
      sv += __shfl_xor(sv, 2);
      sv += __shfl_xor(sv, 4);
      sv += __shfl_xor(sv, 8);
      if (fr == 0) {
        int s = gs0 + wr * 64 + i * 16 + fg * 4 + r;
        atomicAdd(&ssum[(size_t)e * S_TOK + s], sv);
      }
    }
  }
}

// ---- summed = g0*(ssum0+b2sum0)+g1*(ssum1+b2sum1); log_softmax over T ----
__global__ __launch_bounds__(512) void finalize(const float* __restrict__ g,
                                                const float* __restrict__ ssum,
                                                const float* __restrict__ b2sum,
                                                float* __restrict__ out) {
  __shared__ float sA[8];
  __shared__ float sB[2];
  int b = blockIdx.x;
  int t = threadIdx.x;
  int s = b * TDIM + t;
  int lane = t & 63, wid = t >> 6;
  float g0 = g[2*s], g1 = g[2*s+1];
  float v = g0 * (ssum[s] + b2sum[0]) + g1 * (ssum[S_TOK + s] + b2sum[1]);
  float m = v;
  #pragma unroll
  for (int off = 32; off; off >>= 1) m = fmaxf(m, __shfl_xor(m, off));
  if (lane == 0) sA[wid] = m;
  __syncthreads();
  if (t == 0) {
    float mm = sA[0];
    #pragma unroll
    for (int i = 1; i < 8; ++i) mm = fmaxf(mm, sA[i]);
    sB[0] = mm;
  }
  __syncthreads();
  float gm = sB[0];
  float ex = expf(v - gm);
  float sum = ex;
  #pragma unroll
  for (int off = 32; off; off >>= 1) sum += __shfl_xor(sum, off);
  if (lane == 0) sA[wid] = sum;
  __syncthreads();
  if (t == 0) {
    float ss = 0.f;
    #pragma unroll
    for (int i = 0; i < 8; ++i) ss += sA[i];
    sB[1] = logf(ss);
  }
  __syncthreads();
  out[s] = v - gm - sB[1];
}

extern "C" void kernel_launch(void* const* d_in, const int* in_sizes, int n_in,
                              void* d_out, int out_size, void* d_ws, size_t ws_size,
                              hipStream_t stream) {
  const float* x  = (const float*)d_in[0];
  const float* wg = (const float*)d_in[1];
  const float* w1 = (const float*)d_in[2];
  const float* b1 = (const float*)d_in[3];
  const float* w2 = (const float*)d_in[4];
  const float* b2 = (const float*)d_in[5];
  float* out = (float*)d_out;

  char* ws = (char*)d_ws;
  u16*   w1t   = (u16*)ws;                     // 2048*2048*2 = 8,388,608 B
  u16*   xbf   = (u16*)(ws + 8388608);         // 4096*2048*2 = 16,777,216 B
  float* ssum  = (float*)(ws + 25165824);      // 2*4096*4 = 32,768 B
  float* gbuf  = (float*)(ws + 25198592);      // 4096*2*4 = 32,768 B
  float* w2sum = (float*)(ws + 25231360);      // 2048*4 = 8,192 B
  float* b2sum = (float*)(ws + 25239552);      // 8 B

  hipMemsetAsync(ssum, 0, S_TOK * 2 * sizeof(float), stream);
  hipLaunchKernelGGL(prep_w1t,   dim3(4096), dim3(256), 0, stream, w1, w1t);
  hipLaunchKernelGGL(prep_sums,  dim3(513),  dim3(256), 0, stream, w2, b2, w2sum, b2sum);
  hipLaunchKernelGGL(gate_xbf,   dim3(1024), dim3(256), 0, stream, x, wg, gbuf, xbf);
  hipLaunchKernelGGL(gemm_fused, dim3(512),  dim3(512), 0, stream, xbf, w1t, b1, w2sum, ssum);
  hipLaunchKernelGGL(finalize,   dim3(8),    dim3(512), 0, stream, gbuf, ssum, b2sum, out);
}